// Round 1
// 1505.375 us; speedup vs baseline: 1.0011x; 1.0011x over previous
//
#include <hip/hip_runtime.h>
#include <hip/hip_bf16.h>

typedef unsigned short u16;
typedef __bf16 bf16x8 __attribute__((ext_vector_type(8)));
typedef float f32x4 __attribute__((ext_vector_type(4)));

__device__ __forceinline__ u16 f2bf(float v) {
    __hip_bfloat16 h = __float2bfloat16(v);
    return __builtin_bit_cast(u16, h);
}
__device__ __forceinline__ float bf2f(u16 v) {
    __hip_bfloat16 h = __builtin_bit_cast(__hip_bfloat16, v);
    return __bfloat162float(h);
}

// async global -> LDS, 16B per lane. LDS dst must be wave-uniform-base + lane*16.
__device__ __forceinline__ void gld_lds16(const u16* g, u16* l) {
    __builtin_amdgcn_global_load_lds(
        (const __attribute__((address_space(1))) unsigned int*)(const void*)g,
        (__attribute__((address_space(3))) unsigned int*)(void*)l, 16, 0, 0);
}

// ---------------- elementwise / transform kernels ----------------

__global__ void k_convert_bf16(const float* __restrict__ s, u16* __restrict__ d, long n) {
    long i = ((long)blockIdx.x * 256 + threadIdx.x) * 4;
    if (i < n) {
        float4 v = *(const float4*)(s + i);
        u16 a = f2bf(v.x), b = f2bf(v.y), c = f2bf(v.z), e = f2bf(v.w);
        ushort4 o; o.x = a; o.y = b; o.z = c; o.w = e;
        *(ushort4*)(d + i) = o;
    }
}

// dst[c][r] = bf16(src[r][c]); grid (C/32, R/32), block 256
__global__ void k_transpose_f32_bf16(const float* __restrict__ src, u16* __restrict__ dst,
                                     int R, int C, int ld_src, int ld_dst) {
    __shared__ u16 t[32][33];
    int c0 = blockIdx.x * 32, r0 = blockIdx.y * 32;
    int tx = threadIdx.x & 31, ty = threadIdx.x >> 5; // ty 0..7
#pragma unroll
    for (int i = 0; i < 32; i += 8)
        t[ty + i][tx] = f2bf(src[(size_t)(r0 + ty + i) * ld_src + c0 + tx]);
    __syncthreads();
#pragma unroll
    for (int i = 0; i < 32; i += 8)
        dst[(size_t)(c0 + ty + i) * ld_dst + r0 + tx] = t[tx][ty + i];
}

__global__ void k_transpose_u16(const u16* __restrict__ src, u16* __restrict__ dst,
                                int R, int C, int ld_src, int ld_dst) {
    __shared__ u16 t[32][33];
    int c0 = blockIdx.x * 32, r0 = blockIdx.y * 32;
    int tx = threadIdx.x & 31, ty = threadIdx.x >> 5;
#pragma unroll
    for (int i = 0; i < 32; i += 8)
        t[ty + i][tx] = src[(size_t)(r0 + ty + i) * ld_src + c0 + tx];
    __syncthreads();
#pragma unroll
    for (int i = 0; i < 32; i += 8)
        dst[(size_t)(c0 + ty + i) * ld_dst + r0 + tx] = t[tx][ty + i];
}

__global__ void k_rowsum(const float* __restrict__ A, float* __restrict__ r) {
    __shared__ float sm[4];
    const float4* p = (const float4*)(A + (size_t)blockIdx.x * 4096);
    float s = 0.f;
#pragma unroll
    for (int j = 0; j < 4; ++j) {
        float4 v = p[threadIdx.x + j * 256];
        s += v.x + v.y + v.z + v.w;
    }
#pragma unroll
    for (int o = 32; o; o >>= 1) s += __shfl_down(s, o, 64);
    if ((threadIdx.x & 63) == 0) sm[threadIdx.x >> 6] = s;
    __syncthreads();
    if (threadIdx.x == 0) r[blockIdx.x] = sm[0] + sm[1] + sm[2] + sm[3];
}

// row sums of bf16 [4096,4096]; applied to A^T -> column sums of A (0/1 exact in bf16)
__global__ void k_rowsum_bf16(const u16* __restrict__ A, float* __restrict__ r) {
    __shared__ float sm[4];
    const ushort4* p = (const ushort4*)(A + (size_t)blockIdx.x * 4096);
    float s = 0.f;
#pragma unroll
    for (int j = 0; j < 4; ++j) {
        ushort4 v = p[threadIdx.x + j * 256];
        s += bf2f(v.x) + bf2f(v.y) + bf2f(v.z) + bf2f(v.w);
    }
#pragma unroll
    for (int o = 32; o; o >>= 1) s += __shfl_down(s, o, 64);
    if ((threadIdx.x & 63) == 0) sm[threadIdx.x >> 6] = s;
    __syncthreads();
    if (threadIdx.x == 0) r[blockIdx.x] = sm[0] + sm[1] + sm[2] + sm[3];
}

__global__ void k_bias_concat(const float* __restrict__ bq, const float* __restrict__ bk,
                              const float* __restrict__ bv, float* __restrict__ o) {
    int i = blockIdx.x * 256 + threadIdx.x;
    o[i] = i < 1024 ? bq[i] : (i < 2048 ? bk[i - 1024] : bv[i - 2048]);
}

// layernorm over wx0+wx1 (two weighted-projection slabs, fused reduction)
__global__ void k_layernorm(const float* __restrict__ wx0, const float* __restrict__ wx1,
                            const float* __restrict__ gamma,
                            const float* __restrict__ beta, u16* __restrict__ h) {
    __shared__ float sm[8];
    size_t base = (size_t)blockIdx.x * 1024;
    float4 a = ((const float4*)(wx0 + base))[threadIdx.x];
    float4 b = ((const float4*)(wx1 + base))[threadIdx.x];
    float4 v;
    v.x = a.x + b.x; v.y = a.y + b.y; v.z = a.z + b.z; v.w = a.w + b.w;
    float s = v.x + v.y + v.z + v.w;
    float q = v.x * v.x + v.y * v.y + v.z * v.z + v.w * v.w;
#pragma unroll
    for (int o = 32; o; o >>= 1) { s += __shfl_down(s, o, 64); q += __shfl_down(q, o, 64); }
    int lane = threadIdx.x & 63, w = threadIdx.x >> 6;
    if (lane == 0) { sm[w] = s; sm[4 + w] = q; }
    __syncthreads();
    s = sm[0] + sm[1] + sm[2] + sm[3];
    q = sm[4] + sm[5] + sm[6] + sm[7];
    float mu = s * (1.f / 1024.f);
    float var = q * (1.f / 1024.f) - mu * mu;
    float rstd = rsqrtf(var + 1e-5f);
    int c = threadIdx.x * 4;
    ushort4 o;
    o.x = f2bf((v.x - mu) * rstd * gamma[c + 0] + beta[c + 0]);
    o.y = f2bf((v.y - mu) * rstd * gamma[c + 1] + beta[c + 1]);
    o.z = f2bf((v.z - mu) * rstd * gamma[c + 2] + beta[c + 2]);
    o.w = f2bf((v.w - mu) * rstd * gamma[c + 3] + beta[c + 3]);
    *(ushort4*)(h + base + c) = o;
}

__global__ void k_softmax(const float* __restrict__ S, u16* __restrict__ P) {
    __shared__ float sm[8];
    size_t base = (size_t)blockIdx.x * 4096;
    const float4* p = (const float4*)(S + base);
    float4 v[4];
#pragma unroll
    for (int j = 0; j < 4; ++j) v[j] = p[threadIdx.x + j * 256];
    float m = -3.4e38f;
#pragma unroll
    for (int j = 0; j < 4; ++j)
        m = fmaxf(m, fmaxf(fmaxf(v[j].x, v[j].y), fmaxf(v[j].z, v[j].w)));
#pragma unroll
    for (int o = 32; o; o >>= 1) m = fmaxf(m, __shfl_down(m, o, 64));
    int lane = threadIdx.x & 63, w = threadIdx.x >> 6;
    if (lane == 0) sm[w] = m;
    __syncthreads();
    m = fmaxf(fmaxf(sm[0], sm[1]), fmaxf(sm[2], sm[3]));
    float s = 0.f;
#pragma unroll
    for (int j = 0; j < 4; ++j) {
        v[j].x = __expf(v[j].x - m); v[j].y = __expf(v[j].y - m);
        v[j].z = __expf(v[j].z - m); v[j].w = __expf(v[j].w - m);
        s += v[j].x + v[j].y + v[j].z + v[j].w;
    }
#pragma unroll
    for (int o = 32; o; o >>= 1) s += __shfl_down(s, o, 64);
    if (lane == 0) sm[4 + w] = s;
    __syncthreads();
    s = sm[4] + sm[5] + sm[6] + sm[7];
    float inv = 1.f / s;
#pragma unroll
    for (int j = 0; j < 4; ++j) {
        ushort4 o;
        o.x = f2bf(v[j].x * inv); o.y = f2bf(v[j].y * inv);
        o.z = f2bf(v[j].z * inv); o.w = f2bf(v[j].w * inv);
        *(ushort4*)(P + base + (size_t)(threadIdx.x + j * 256) * 4) = o;
    }
}

// ---------------- the GEMM: C[M,N] = A[M,K] @ B[K,N], B given transposed [N,K] ----------------
// 128x128 tile, BK=32, 4 waves of 4x4 mfma_f32_16x16x32_bf16 (m97 structure).

#define EPI_M_BUILD 0
#define EPI_F32     1
#define EPI_QKV     3
#define EPI_SCORES  4
#define EPI_BF16    5
#define EPI_FINAL   6

template <int EPI>
__launch_bounds__(256, 2)
__global__ void gemm_bt(const u16* __restrict__ A, const u16* __restrict__ Bt,
                        int K, int lda, int ldb, int ldc,
                        void* __restrict__ Cout,
                        const float* __restrict__ e0, const float* __restrict__ e1,
                        const float* __restrict__ e2, const float* __restrict__ e3,
                        float scale, int kidx, size_t zb) {
    __shared__ __align__(16) u16 As[128 * 32];
    __shared__ __align__(16) u16 Bs[128 * 32];
    const int tid = threadIdx.x;
    const int m0 = blockIdx.y * 128, n0 = blockIdx.x * 128;
    const int lane = tid & 63, wave = tid >> 6;
    const int wm = (wave >> 1) * 64, wn = (wave & 1) * 64;
    const int fr = lane & 15, quad = lane >> 4;

    Bt += (size_t)blockIdx.z * zb;

    f32x4 acc[4][4] = {};

    // staging: 512 16B chunks per tile; chunk c -> row c>>2, k-part (c&3)*8
    const int ar = tid >> 2, ak = (tid & 3) * 8;
    const u16* gA0 = A + (size_t)(m0 + ar) * lda + ak;
    const u16* gA1 = gA0 + (size_t)64 * lda;
    const u16* gB0 = Bt + (size_t)(n0 + ar) * ldb + ak;
    const u16* gB1 = gB0 + (size_t)64 * ldb;
    u16* lA0 = As + tid * 8;
    u16* lA1 = As + (tid + 256) * 8;
    u16* lB0 = Bs + tid * 8;
    u16* lB1 = Bs + (tid + 256) * 8;

    for (int kk = 0; kk < K; kk += 32) {
        __syncthreads();                 // protect LDS from previous iteration's readers
        gld_lds16(gA0 + kk, lA0);
        gld_lds16(gA1 + kk, lA1);
        gld_lds16(gB0 + kk, lB0);
        gld_lds16(gB1 + kk, lB1);
        __syncthreads();                 // drains vmcnt before barrier

        bf16x8 af[4], bfv[4];
#pragma unroll
        for (int i = 0; i < 4; ++i)
            af[i] = *(const bf16x8*)(As + (wm + i * 16 + fr) * 32 + quad * 8);
#pragma unroll
        for (int i = 0; i < 4; ++i)
            bfv[i] = *(const bf16x8*)(Bs + (wn + i * 16 + fr) * 32 + quad * 8);
#pragma unroll
        for (int mi = 0; mi < 4; ++mi)
#pragma unroll
            for (int ni = 0; ni < 4; ++ni)
                acc[mi][ni] = __builtin_amdgcn_mfma_f32_16x16x32_bf16(af[mi], bfv[ni], acc[mi][ni], 0, 0, 0);
    }

    // epilogue: C/D layout col = lane&15, row = quad*4 + reg
#pragma unroll
    for (int mi = 0; mi < 4; ++mi) {
#pragma unroll
        for (int r = 0; r < 4; ++r) {
            int row = m0 + wm + mi * 16 + quad * 4 + r;
#pragma unroll
            for (int ni = 0; ni < 4; ++ni) {
                int col = n0 + wn + ni * 16 + fr;
                float v = acc[mi][ni][r];
                size_t ci = (size_t)row * ldc + col;
                if constexpr (EPI == EPI_M_BUILD) {
                    size_t gi = (size_t)row * 4096 + col;
                    float denom = e2[row] + e3[col] - v + 1e-6f;
                    ((u16*)Cout)[ci] = f2bf(e0[gi] + v / denom + e1[gi]);
                } else if constexpr (EPI == EPI_F32) {
                    ((float*)Cout)[ci] = v;
                } else if constexpr (EPI == EPI_QKV) {
                    ((u16*)Cout)[ci] = f2bf(v + e0[col]);
                } else if constexpr (EPI == EPI_SCORES) {
                    ((float*)Cout)[ci] = v * scale + e0[(size_t)row * 4096 + col];
                } else if constexpr (EPI == EPI_BF16) {
                    ((u16*)Cout)[ci] = f2bf(v);
                } else { // EPI_FINAL
                    float y = v + e0[col] + e1[(size_t)row * 4096 + col];
                    ((float*)Cout)[ci] = y > 0.f ? y : 0.f;
                }
            }
        }
    }
}

// ---------------- fused weighted projection: out_z = sum_{k in slab z} w[:,k]*(x@W_k + b_k) ----
// grid (8, 32, 2): z picks 5 of the 10 weight slabs; per block: outer slab loop, inner K=4096
// m97-structure GEMM into a scratch accumulator, then per-slab fold acc += w*(acck + b).
// Plain f32 stores (no atomics); the two z-slabs are summed inside k_layernorm.

__launch_bounds__(256, 2)
__global__ void gemm_wsum(const u16* __restrict__ A, const u16* __restrict__ Bt,
                          const float* __restrict__ wts, const float* __restrict__ bst,
                          float* __restrict__ C0, float* __restrict__ C1) {
    __shared__ __align__(16) u16 As[128 * 32];
    __shared__ __align__(16) u16 Bs[128 * 32];
    const int tid = threadIdx.x;
    const int m0 = blockIdx.y * 128, n0 = blockIdx.x * 128;
    const int lane = tid & 63, wave = tid >> 6;
    const int wm = (wave >> 1) * 64, wn = (wave & 1) * 64;
    const int fr = lane & 15, quad = lane >> 4;
    const int k0 = blockIdx.z * 5;

    const int ar = tid >> 2, ak = (tid & 3) * 8;
    const u16* gA0 = A + (size_t)(m0 + ar) * 4096 + ak;
    const u16* gA1 = gA0 + (size_t)64 * 4096;
    u16* lA0 = As + tid * 8;
    u16* lA1 = As + (tid + 256) * 8;
    u16* lB0 = Bs + tid * 8;
    u16* lB1 = Bs + (tid + 256) * 8;

    f32x4 acc[4][4] = {};

    for (int s = 0; s < 5; ++s) {
        const int k = k0 + s;
        const u16* gB0 = Bt + (size_t)k * 1024 * 4096 + (size_t)(n0 + ar) * 4096 + ak;
        const u16* gB1 = gB0 + (size_t)64 * 4096;

        f32x4 acck[4][4] = {};
        for (int kk = 0; kk < 4096; kk += 32) {
            __syncthreads();
            gld_lds16(gA0 + kk, lA0);
            gld_lds16(gA1 + kk, lA1);
            gld_lds16(gB0 + kk, lB0);
            gld_lds16(gB1 + kk, lB1);
            __syncthreads();

            bf16x8 af[4], bfv[4];
#pragma unroll
            for (int i = 0; i < 4; ++i)
                af[i] = *(const bf16x8*)(As + (wm + i * 16 + fr) * 32 + quad * 8);
#pragma unroll
            for (int i = 0; i < 4; ++i)
                bfv[i] = *(const bf16x8*)(Bs + (wn + i * 16 + fr) * 32 + quad * 8);
#pragma unroll
            for (int mi = 0; mi < 4; ++mi)
#pragma unroll
                for (int ni = 0; ni < 4; ++ni)
                    acck[mi][ni] = __builtin_amdgcn_mfma_f32_16x16x32_bf16(af[mi], bfv[ni], acck[mi][ni], 0, 0, 0);
        }

        // fold: acc += w[row,k] * (acck + b_k[col])
        float bv[4];
#pragma unroll
        for (int ni = 0; ni < 4; ++ni)
            bv[ni] = bst[(size_t)k * 1024 + n0 + wn + ni * 16 + fr];
#pragma unroll
        for (int mi = 0; mi < 4; ++mi) {
#pragma unroll
            for (int r = 0; r < 4; ++r) {
                int row = m0 + wm + mi * 16 + quad * 4 + r;
                float w = wts[(size_t)row * 10 + k];
#pragma unroll
                for (int ni = 0; ni < 4; ++ni)
                    acc[mi][ni][r] += w * (acck[mi][ni][r] + bv[ni]);
            }
        }
    }

    float* Cout = blockIdx.z ? C1 : C0;
#pragma unroll
    for (int mi = 0; mi < 4; ++mi) {
#pragma unroll
        for (int r = 0; r < 4; ++r) {
            int row = m0 + wm + mi * 16 + quad * 4 + r;
#pragma unroll
            for (int ni = 0; ni < 4; ++ni) {
                int col = n0 + wn + ni * 16 + fr;
                Cout[(size_t)row * 1024 + col] = acc[mi][ni][r];
            }
        }
    }
}

// ---------------- launch ----------------

extern "C" void kernel_launch(void* const* d_in, const int* in_sizes, int n_in,
                              void* d_out, int out_size, void* d_ws, size_t ws_size,
                              hipStream_t stream) {
    (void)in_sizes; (void)n_in; (void)out_size; (void)ws_size;
    const float* x   = (const float*)d_in[0];
    const float* A   = (const float*)d_in[1];
    const float* gm  = (const float*)d_in[2];
    const float* wts = (const float*)d_in[3];
    const float* Wst = (const float*)d_in[4];
    const float* bst = (const float*)d_in[5];
    const float* Wq  = (const float*)d_in[6];
    const float* bq  = (const float*)d_in[7];
    const float* Wk  = (const float*)d_in[8];
    const float* bk  = (const float*)d_in[9];
    const float* Wv  = (const float*)d_in[10];
    const float* bv  = (const float*)d_in[11];
    const float* Wo  = (const float*)d_in[12];
    const float* bo  = (const float*)d_in[13];
    const float* gamma = (const float*)d_in[14];
    const float* beta  = (const float*)d_in[15];
    float* out = (float*)d_out;
    char* ws = (char*)d_ws;

    const int N = 4096, DM = 1024;
    const size_t MB32 = 33554432UL;
    // round-1 arena (proven), plus WallT at [0,80 MB) for phase 3
    u16*   A_bf   = (u16*)(ws + 0);               // dead after inter GEMM
    u16*   A_bfT  = (u16*)(ws + MB32);            // dead after inter GEMM
    float* scores = (float*)(ws + 0);             // written phase 7
    u16*   x_bfT  = (u16*)(ws + 2 * MB32);        // dead after dng GEMM
    u16*   attn   = (u16*)(ws + 2 * MB32);        // written phase 8
    u16*   x_bf   = (u16*)(ws + 3 * MB32);        // dead after weighted GEMM
    u16*   WqkvT  = (u16*)(ws + 3 * MB32);        // written phase 4
    float* bqkv   = (float*)(ws + 3 * MB32 + 6291456UL);
    u16*   QKV    = (u16*)(ws + 3 * MB32 + 6307840UL);
    u16*   M_bf   = (u16*)(ws + 4 * MB32);        // dead after dng GEMM
    float* wxf2   = (float*)(ws + 4 * MB32);      // phase-3 slab 1 (M_bf dead); dead after LN
    u16*   WallT  = (u16*)(ws + 0);               // [0,80MB) phase 3 (A_bf/A_bfT/x_bfT dead)
    u16*   V_T    = (u16*)(ws + 4 * MB32);        // written phase 6 (after LN reads wxf2)
    u16*   WoT    = (u16*)(ws + 4 * MB32 + 8388608UL);
    u16*   out_bf = (u16*)(ws + 4 * MB32 + 16777216UL);
    float* dng    = (float*)(ws + 5 * MB32);      // 64 MB, lives to end
    float* wxf    = (float*)(ws + 5 * MB32 + 67108864UL);  // phase-3 slab 0
    u16*   h_bf   = (u16*)(ws + 5 * MB32 + 83886080UL);
    float* rowS   = (float*)(ws + 5 * MB32 + 92274688UL);
    float* colS   = (float*)(ws + 5 * MB32 + 92291072UL);

    // phase 0: conversions + degree sums
    k_convert_bf16<<<16384, 256, 0, stream>>>(A, A_bf, (long)N * N);
    k_transpose_f32_bf16<<<dim3(128, 128), 256, 0, stream>>>(A, A_bfT, N, N, N, N);
    k_convert_bf16<<<16384, 256, 0, stream>>>(x, x_bf, (long)N * N);
    k_transpose_f32_bf16<<<dim3(128, 128), 256, 0, stream>>>(x, x_bfT, N, N, N, N);
    k_rowsum<<<N, 256, 0, stream>>>(A, rowS);
    k_rowsum_bf16<<<N, 256, 0, stream>>>(A_bfT, colS);   // column sums of A via A^T row sums

    // phase 1: inter = A@A, epilogue builds M = A + sim + gm (bf16)
    gemm_bt<EPI_M_BUILD><<<dim3(32, 32), 256, 0, stream>>>(
        A_bf, A_bfT, N, N, N, N, M_bf, A, gm, rowS, colS, 0.f, 0, 0);

    // phase 2: dng = M @ x (fp32)
    gemm_bt<EPI_F32><<<dim3(32, 32), 256, 0, stream>>>(
        M_bf, x_bfT, N, N, N, N, dng, nullptr, nullptr, nullptr, nullptr, 0.f, 0, 0);

    // phase 3: weighted_x = sum_k w[:,k]*(x@W_k + b_k)
    // 10 per-k transposes into one 80MB slab, then ONE slab-fused GEMM:
    // grid (8,32,2) = 512 blocks (2/CU); each block loops 5 slabs with K=4096 each,
    // folding acc += w*(acck+b) per slab. No atomics; two plain f32 slabs,
    // summed inside k_layernorm.
    for (int k = 0; k < 10; ++k)
        k_transpose_f32_bf16<<<dim3(32, 128), 256, 0, stream>>>(
            Wst + (size_t)k * N * DM, WallT + (size_t)k * DM * N, N, DM, DM, N);
    gemm_wsum<<<dim3(8, 32, 2), 256, 0, stream>>>(x_bf, WallT, wts, bst, wxf, wxf2);

    // phase 4: QKV weight prep + layernorm (fuses the 2-slab reduction)
    k_transpose_f32_bf16<<<dim3(32, 32), 256, 0, stream>>>(Wq, WqkvT, DM, DM, DM, DM);
    k_transpose_f32_bf16<<<dim3(32, 32), 256, 0, stream>>>(Wk, WqkvT + (size_t)DM * DM, DM, DM, DM, DM);
    k_transpose_f32_bf16<<<dim3(32, 32), 256, 0, stream>>>(Wv, WqkvT + 2 * (size_t)DM * DM, DM, DM, DM, DM);
    k_bias_concat<<<12, 256, 0, stream>>>(bq, bk, bv, bqkv);
    k_layernorm<<<N, 256, 0, stream>>>(wxf, wxf2, gamma, beta, h_bf);

    // phase 5: QKV = h @ [Wq|Wk|Wv] + bias  (bf16, ldc=3072)
    gemm_bt<EPI_QKV><<<dim3(24, 32), 256, 0, stream>>>(
        h_bf, WqkvT, DM, DM, DM, 3072, QKV, bqkv, nullptr, nullptr, nullptr, 0.f, 0, 0);

    // phase 6: V^T
    k_transpose_u16<<<dim3(32, 128), 256, 0, stream>>>(QKV + 2048, V_T, N, DM, 3072, N);

    // phase 7: scores = Q@K^T/32 + dng (fp32)
    gemm_bt<EPI_SCORES><<<dim3(32, 32), 256, 0, stream>>>(
        QKV, QKV + 1024, DM, 3072, 3072, N, scores, dng, nullptr, nullptr, nullptr, 0.03125f, 0, 0);

    // phase 8: softmax rows -> attn (bf16)
    k_softmax<<<N, 256, 0, stream>>>(scores, attn);

    // phase 9: out = attn @ V (bf16)
    gemm_bt<EPI_BF16><<<dim3(8, 32), 256, 0, stream>>>(
        attn, V_T, N, N, N, DM, out_bf, nullptr, nullptr, nullptr, nullptr, 0.f, 0, 0);

    // phase 10: y = relu(out @ Wo + bo + dng) -> d_out (fp32)
    k_transpose_f32_bf16<<<dim3(128, 32), 256, 0, stream>>>(Wo, WoT, DM, N, N, DM);
    gemm_bt<EPI_FINAL><<<dim3(32, 32), 256, 0, stream>>>(
        out_bf, WoT, DM, DM, DM, N, out, bo, dng, nullptr, nullptr, 0.f, 0, 0);
}

// Round 2
// 1392.306 us; speedup vs baseline: 1.0825x; 1.0812x over previous
//
#include <hip/hip_runtime.h>
#include <hip/hip_bf16.h>

typedef unsigned short u16;
typedef __bf16 bf16x8 __attribute__((ext_vector_type(8)));
typedef float f32x4 __attribute__((ext_vector_type(4)));

__device__ __forceinline__ u16 f2bf(float v) {
    __hip_bfloat16 h = __float2bfloat16(v);
    return __builtin_bit_cast(u16, h);
}
__device__ __forceinline__ float bf2f(u16 v) {
    __hip_bfloat16 h = __builtin_bit_cast(__hip_bfloat16, v);
    return __bfloat162float(h);
}

// async global -> LDS, 16B per lane. LDS dst must be wave-uniform-base + lane*16.
__device__ __forceinline__ void gld_lds16(const u16* g, u16* l) {
    __builtin_amdgcn_global_load_lds(
        (const __attribute__((address_space(1))) unsigned int*)(const void*)g,
        (__attribute__((address_space(3))) unsigned int*)(void*)l, 16, 0, 0);
}

// ---------------- elementwise / transform kernels ----------------

__global__ void k_convert_bf16(const float* __restrict__ s, u16* __restrict__ d, long n) {
    long i = ((long)blockIdx.x * 256 + threadIdx.x) * 4;
    if (i < n) {
        float4 v = *(const float4*)(s + i);
        u16 a = f2bf(v.x), b = f2bf(v.y), c = f2bf(v.z), e = f2bf(v.w);
        ushort4 o; o.x = a; o.y = b; o.z = c; o.w = e;
        *(ushort4*)(d + i) = o;
    }
}

__global__ void k_zero_f32(float* __restrict__ p) {
    float4 z; z.x = z.y = z.z = z.w = 0.f;
    ((float4*)p)[(size_t)blockIdx.x * 256 + threadIdx.x] = z;
}

// dst[c][r] = bf16(src[r][c]); grid (C/32, R/32), block 256
__global__ void k_transpose_f32_bf16(const float* __restrict__ src, u16* __restrict__ dst,
                                     int R, int C, int ld_src, int ld_dst) {
    __shared__ u16 t[32][33];
    int c0 = blockIdx.x * 32, r0 = blockIdx.y * 32;
    int tx = threadIdx.x & 31, ty = threadIdx.x >> 5; // ty 0..7
#pragma unroll
    for (int i = 0; i < 32; i += 8)
        t[ty + i][tx] = f2bf(src[(size_t)(r0 + ty + i) * ld_src + c0 + tx]);
    __syncthreads();
#pragma unroll
    for (int i = 0; i < 32; i += 8)
        dst[(size_t)(c0 + ty + i) * ld_dst + r0 + tx] = t[tx][ty + i];
}

__global__ void k_transpose_u16(const u16* __restrict__ src, u16* __restrict__ dst,
                                int R, int C, int ld_src, int ld_dst) {
    __shared__ u16 t[32][33];
    int c0 = blockIdx.x * 32, r0 = blockIdx.y * 32;
    int tx = threadIdx.x & 31, ty = threadIdx.x >> 5;
#pragma unroll
    for (int i = 0; i < 32; i += 8)
        t[ty + i][tx] = src[(size_t)(r0 + ty + i) * ld_src + c0 + tx];
    __syncthreads();
#pragma unroll
    for (int i = 0; i < 32; i += 8)
        dst[(size_t)(c0 + ty + i) * ld_dst + r0 + tx] = t[tx][ty + i];
}

__global__ void k_rowsum(const float* __restrict__ A, float* __restrict__ r) {
    __shared__ float sm[4];
    const float4* p = (const float4*)(A + (size_t)blockIdx.x * 4096);
    float s = 0.f;
#pragma unroll
    for (int j = 0; j < 4; ++j) {
        float4 v = p[threadIdx.x + j * 256];
        s += v.x + v.y + v.z + v.w;
    }
#pragma unroll
    for (int o = 32; o; o >>= 1) s += __shfl_down(s, o, 64);
    if ((threadIdx.x & 63) == 0) sm[threadIdx.x >> 6] = s;
    __syncthreads();
    if (threadIdx.x == 0) r[blockIdx.x] = sm[0] + sm[1] + sm[2] + sm[3];
}

// row sums of bf16 [4096,4096]; applied to A^T -> column sums of A (0/1 exact in bf16)
__global__ void k_rowsum_bf16(const u16* __restrict__ A, float* __restrict__ r) {
    __shared__ float sm[4];
    const ushort4* p = (const ushort4*)(A + (size_t)blockIdx.x * 4096);
    float s = 0.f;
#pragma unroll
    for (int j = 0; j < 4; ++j) {
        ushort4 v = p[threadIdx.x + j * 256];
        s += bf2f(v.x) + bf2f(v.y) + bf2f(v.z) + bf2f(v.w);
    }
#pragma unroll
    for (int o = 32; o; o >>= 1) s += __shfl_down(s, o, 64);
    if ((threadIdx.x & 63) == 0) sm[threadIdx.x >> 6] = s;
    __syncthreads();
    if (threadIdx.x == 0) r[blockIdx.x] = sm[0] + sm[1] + sm[2] + sm[3];
}

__global__ void k_bias_concat(const float* __restrict__ bq, const float* __restrict__ bk,
                              const float* __restrict__ bv, float* __restrict__ o) {
    int i = blockIdx.x * 256 + threadIdx.x;
    o[i] = i < 1024 ? bq[i] : (i < 2048 ? bk[i - 1024] : bv[i - 2048]);
}

__global__ void k_layernorm(const float* __restrict__ wx, const float* __restrict__ gamma,
                            const float* __restrict__ beta, u16* __restrict__ h) {
    __shared__ float sm[8];
    size_t base = (size_t)blockIdx.x * 1024;
    float4 v = ((const float4*)(wx + base))[threadIdx.x];
    float s = v.x + v.y + v.z + v.w;
    float q = v.x * v.x + v.y * v.y + v.z * v.z + v.w * v.w;
#pragma unroll
    for (int o = 32; o; o >>= 1) { s += __shfl_down(s, o, 64); q += __shfl_down(q, o, 64); }
    int lane = threadIdx.x & 63, w = threadIdx.x >> 6;
    if (lane == 0) { sm[w] = s; sm[4 + w] = q; }
    __syncthreads();
    s = sm[0] + sm[1] + sm[2] + sm[3];
    q = sm[4] + sm[5] + sm[6] + sm[7];
    float mu = s * (1.f / 1024.f);
    float var = q * (1.f / 1024.f) - mu * mu;
    float rstd = rsqrtf(var + 1e-5f);
    int c = threadIdx.x * 4;
    ushort4 o;
    o.x = f2bf((v.x - mu) * rstd * gamma[c + 0] + beta[c + 0]);
    o.y = f2bf((v.y - mu) * rstd * gamma[c + 1] + beta[c + 1]);
    o.z = f2bf((v.z - mu) * rstd * gamma[c + 2] + beta[c + 2]);
    o.w = f2bf((v.w - mu) * rstd * gamma[c + 3] + beta[c + 3]);
    *(ushort4*)(h + base + c) = o;
}

__global__ void k_softmax(const float* __restrict__ S, u16* __restrict__ P) {
    __shared__ float sm[8];
    size_t base = (size_t)blockIdx.x * 4096;
    const float4* p = (const float4*)(S + base);
    float4 v[4];
#pragma unroll
    for (int j = 0; j < 4; ++j) v[j] = p[threadIdx.x + j * 256];
    float m = -3.4e38f;
#pragma unroll
    for (int j = 0; j < 4; ++j)
        m = fmaxf(m, fmaxf(fmaxf(v[j].x, v[j].y), fmaxf(v[j].z, v[j].w)));
#pragma unroll
    for (int o = 32; o; o >>= 1) m = fmaxf(m, __shfl_down(m, o, 64));
    int lane = threadIdx.x & 63, w = threadIdx.x >> 6;
    if (lane == 0) sm[w] = m;
    __syncthreads();
    m = fmaxf(fmaxf(sm[0], sm[1]), fmaxf(sm[2], sm[3]));
    float s = 0.f;
#pragma unroll
    for (int j = 0; j < 4; ++j) {
        v[j].x = __expf(v[j].x - m); v[j].y = __expf(v[j].y - m);
        v[j].z = __expf(v[j].z - m); v[j].w = __expf(v[j].w - m);
        s += v[j].x + v[j].y + v[j].z + v[j].w;
    }
#pragma unroll
    for (int o = 32; o; o >>= 1) s += __shfl_down(s, o, 64);
    if (lane == 0) sm[4 + w] = s;
    __syncthreads();
    s = sm[4] + sm[5] + sm[6] + sm[7];
    float inv = 1.f / s;
#pragma unroll
    for (int j = 0; j < 4; ++j) {
        ushort4 o;
        o.x = f2bf(v[j].x * inv); o.y = f2bf(v[j].y * inv);
        o.z = f2bf(v[j].z * inv); o.w = f2bf(v[j].w * inv);
        *(ushort4*)(P + base + (size_t)(threadIdx.x + j * 256) * 4) = o;
    }
}

#define EPI_M_BUILD 0
#define EPI_F32     1
#define EPI_WEIGHTED 2
#define EPI_QKV     3
#define EPI_SCORES  4
#define EPI_BF16    5
#define EPI_FINAL   6

// ---------------- m97-structure GEMM (kept for skinny outputs: phase 9) ----------------

template <int EPI>
__launch_bounds__(256, 2)
__global__ void gemm_bt(const u16* __restrict__ A, const u16* __restrict__ Bt,
                        int K, int lda, int ldb, int ldc,
                        void* __restrict__ Cout,
                        const float* __restrict__ e0, const float* __restrict__ e1,
                        const float* __restrict__ e2, const float* __restrict__ e3,
                        float scale, int kidx, size_t zb) {
    __shared__ __align__(16) u16 As[128 * 32];
    __shared__ __align__(16) u16 Bs[128 * 32];
    const int tid = threadIdx.x;
    const int m0 = blockIdx.y * 128, n0 = blockIdx.x * 128;
    const int lane = tid & 63, wave = tid >> 6;
    const int wm = (wave >> 1) * 64, wn = (wave & 1) * 64;
    const int fr = lane & 15, quad = lane >> 4;

    Bt += (size_t)blockIdx.z * zb;

    f32x4 acc[4][4] = {};

    const int ar = tid >> 2, ak = (tid & 3) * 8;
    const u16* gA0 = A + (size_t)(m0 + ar) * lda + ak;
    const u16* gA1 = gA0 + (size_t)64 * lda;
    const u16* gB0 = Bt + (size_t)(n0 + ar) * ldb + ak;
    const u16* gB1 = gB0 + (size_t)64 * ldb;
    u16* lA0 = As + tid * 8;
    u16* lA1 = As + (tid + 256) * 8;
    u16* lB0 = Bs + tid * 8;
    u16* lB1 = Bs + (tid + 256) * 8;

    for (int kk = 0; kk < K; kk += 32) {
        __syncthreads();
        gld_lds16(gA0 + kk, lA0);
        gld_lds16(gA1 + kk, lA1);
        gld_lds16(gB0 + kk, lB0);
        gld_lds16(gB1 + kk, lB1);
        __syncthreads();

        bf16x8 af[4], bfv[4];
#pragma unroll
        for (int i = 0; i < 4; ++i)
            af[i] = *(const bf16x8*)(As + (wm + i * 16 + fr) * 32 + quad * 8);
#pragma unroll
        for (int i = 0; i < 4; ++i)
            bfv[i] = *(const bf16x8*)(Bs + (wn + i * 16 + fr) * 32 + quad * 8);
#pragma unroll
        for (int mi = 0; mi < 4; ++mi)
#pragma unroll
            for (int ni = 0; ni < 4; ++ni)
                acc[mi][ni] = __builtin_amdgcn_mfma_f32_16x16x32_bf16(af[mi], bfv[ni], acc[mi][ni], 0, 0, 0);
    }

#pragma unroll
    for (int mi = 0; mi < 4; ++mi) {
#pragma unroll
        for (int r = 0; r < 4; ++r) {
            int row = m0 + wm + mi * 16 + quad * 4 + r;
#pragma unroll
            for (int ni = 0; ni < 4; ++ni) {
                int col = n0 + wn + ni * 16 + fr;
                float v = acc[mi][ni][r];
                size_t ci = (size_t)row * ldc + col;
                if constexpr (EPI == EPI_BF16) {
                    ((u16*)Cout)[ci] = f2bf(v);
                } else if constexpr (EPI == EPI_F32) {
                    ((float*)Cout)[ci] = v;
                }
            }
        }
    }
}

// ---------------- 256x256 8-phase GEMM (T1+T2+T3+T4+T5), BK=64, 512 threads ----------------
// LDS 128KB: 2 bufs x (A 256x64 + B 256x64) bf16. A slot s holds block rows
// [s*64,s*64+64) u [128+s*64, 128+s*64+64) so wave_m groups free slot s after phase 2s+1.
// Per K-tile: 4 phases, phase q = M-quarter q, 16 MFMA each, full K=64.
// Issue schedule per tile t: ph0: A1(t+1); ph2: A0(t+2); ph3: B0(t+2),B1(t+2).
// Single counted vmcnt(8) per tile at ph0 (covers incoming tile; last 4 half-tiles = 8 loads
// stay in flight). XOR k-chunk swizzle: phys_kc = kc ^ (row&7), pre-swizzled on the global
// source (global_load_lds writes linearly), swizzled on ds_read.

#define FENCE() asm volatile("" ::: "memory")
#define BAR8() { FENCE(); __builtin_amdgcn_s_barrier(); FENCE(); }

template <int EPI>
__launch_bounds__(512, 2)
__global__ void gemm8(const u16* __restrict__ Ag, const u16* __restrict__ Bt,
                      int K, int lda, int ldb, int ldc, void* __restrict__ Cout,
                      const float* __restrict__ e0, const float* __restrict__ e1,
                      const float* __restrict__ e2, const float* __restrict__ e3,
                      float scale) {
    __shared__ __align__(16) u16 S[65536];
    const int tid = threadIdx.x;
    const int bid = blockIdx.y * gridDim.x + blockIdx.x;
    const int nwg = gridDim.x * gridDim.y;          // always a multiple of 8 here
    const int swz = (bid & 7) * (nwg >> 3) + (bid >> 3);
    const int m0 = (swz / gridDim.x) * 256;
    const int n0 = (swz % gridDim.x) * 256;

    // staging: thread covers 16B at (row srow, k-chunk (tid&7)^(srow&7)) of a 64-row issue
    const int srow = tid >> 3;
    const int skc8 = ((tid & 7) ^ (srow & 7)) * 8;
    const u16* gA = Ag + (size_t)(m0 + srow) * lda + skc8;
    const u16* gB = Bt + (size_t)(n0 + srow) * ldb + skc8;
    u16* dst = S + tid * 8;

    const int lane = tid & 63, wave = tid >> 6;
    const int wn = (wave & 3) * 64;       // B row base (wave_n)
    const int wmA = (wave >> 2) * 64;     // A phys-row base within slot (wave_m)
    const int fr = lane & 15, quad = lane >> 4;
    const int kc0 = (quad ^ (fr & 7)) * 8;          // swizzled k-chunk, ks=0
    const int kc1 = ((quad ^ (fr & 7)) ^ 4) * 8;    // ks=1

#define ISSUE_A(b, s, kk) { \
    gld_lds16(gA + (size_t)((s) * 64) * lda + (kk), dst + (b) * 32768 + (s) * 8192); \
    gld_lds16(gA + (size_t)((s) * 64 + 128) * lda + (kk), dst + (b) * 32768 + (s) * 8192 + 4096); }
#define ISSUE_B(b, s, kk) { \
    gld_lds16(gB + (size_t)((s) * 128) * ldb + (kk), dst + (b) * 32768 + 16384 + (s) * 8192); \
    gld_lds16(gB + (size_t)((s) * 128 + 64) * ldb + (kk), dst + (b) * 32768 + 16384 + (s) * 8192 + 4096); }

    // prologue: tile0 fully + tile1's A0,B0,B1 (A1(1) issued at t=0 ph0)
    ISSUE_A(0, 0, 0); ISSUE_B(0, 0, 0); ISSUE_B(0, 1, 0); ISSUE_A(0, 1, 0);
    ISSUE_A(1, 0, 64); ISSUE_B(1, 0, 64); ISSUE_B(1, 1, 64);

    f32x4 acc[8][4] = {};
    const int NT = K >> 6;

#define AR8(q, f, ks) (*(const bf16x8*)(SA + (((q) >> 1) * 128 + wmA + ((q) & 1) * 32 + (f) * 16 + fr) * 64 + ((ks) ? kc1 : kc0)))
#define PHASE(q) { \
    bf16x8 a00 = AR8(q, 0, 0), a01 = AR8(q, 0, 1), a10 = AR8(q, 1, 0), a11 = AR8(q, 1, 1); \
    __builtin_amdgcn_s_setprio(1); \
    _Pragma("unroll") \
    for (int fn = 0; fn < 4; ++fn) { \
        acc[2 * (q)][fn]     = __builtin_amdgcn_mfma_f32_16x16x32_bf16(a00, bfr[fn][0], acc[2 * (q)][fn], 0, 0, 0); \
        acc[2 * (q) + 1][fn] = __builtin_amdgcn_mfma_f32_16x16x32_bf16(a10, bfr[fn][0], acc[2 * (q) + 1][fn], 0, 0, 0); \
    } \
    _Pragma("unroll") \
    for (int fn = 0; fn < 4; ++fn) { \
        acc[2 * (q)][fn]     = __builtin_amdgcn_mfma_f32_16x16x32_bf16(a01, bfr[fn][1], acc[2 * (q)][fn], 0, 0, 0); \
        acc[2 * (q) + 1][fn] = __builtin_amdgcn_mfma_f32_16x16x32_bf16(a11, bfr[fn][1], acc[2 * (q) + 1][fn], 0, 0, 0); \
    } \
    __builtin_amdgcn_s_setprio(0); \
    asm volatile("s_waitcnt lgkmcnt(0)" ::: "memory"); }

    for (int t = 0; t < NT; ++t) {
        const int b = t & 1;
        const u16* SA = S + b * 32768;
        const u16* SB = SA + 16384;
        if (t + 1 < NT) ISSUE_A(b ^ 1, 1, (t + 1) * 64);     // A1(t+1)
        if (t < NT - 1) { asm volatile("s_waitcnt vmcnt(8)" ::: "memory"); }
        else            { asm volatile("s_waitcnt vmcnt(0)" ::: "memory"); }
        BAR8();                                              // tile t fully resident
        bf16x8 bfr[4][2];
#pragma unroll
        for (int fn = 0; fn < 4; ++fn) {
            bfr[fn][0] = *(const bf16x8*)(SB + (wn + fn * 16 + fr) * 64 + kc0);
            bfr[fn][1] = *(const bf16x8*)(SB + (wn + fn * 16 + fr) * 64 + kc1);
        }
        PHASE(0);
        BAR8();                                              // B slots + A0(q0 part) readers done
        PHASE(1);
        BAR8();                                              // A0 slot fully free
        if (t + 2 < NT) ISSUE_A(b, 0, (t + 2) * 64);         // A0(t+2) -> current buf
        PHASE(2);
        BAR8();
        if (t + 2 < NT) { ISSUE_B(b, 0, (t + 2) * 64); ISSUE_B(b, 1, (t + 2) * 64); }
        PHASE(3);
        BAR8();                                              // A1 slot free for next-tile ph0 issue
    }

    // epilogue: C row = m0 + wave_m*128 + fm*16 + quad*4 + r ; col = n0 + wn + fn*16 + fr
    const int wmC = (wave >> 2) * 128;
#pragma unroll
    for (int fm = 0; fm < 8; ++fm) {
#pragma unroll
        for (int r = 0; r < 4; ++r) {
            const int row = m0 + wmC + fm * 16 + quad * 4 + r;
#pragma unroll
            for (int fn = 0; fn < 4; ++fn) {
                const int col = n0 + wn + fn * 16 + fr;
                float vv = acc[fm][fn][r];
                if constexpr (EPI == EPI_M_BUILD) {
                    size_t gi = (size_t)row * 4096 + col;
                    float denom = e2[row] + e3[col] - vv + 1e-6f;
                    ((u16*)Cout)[gi] = f2bf(e0[gi] + vv / denom + e1[gi]);
                } else if constexpr (EPI == EPI_F32) {
                    ((float*)Cout)[(size_t)row * ldc + col] = vv;
                } else if constexpr (EPI == EPI_WEIGHTED) {
                    // col = k*1024 + o ; e0 = wts[N][10], e1 = bst flattened [10*1024]
                    atomicAdd((float*)Cout + (size_t)row * 1024 + (col & 1023),
                              e0[(size_t)row * 10 + (col >> 10)] * (vv + e1[col]));
                } else if constexpr (EPI == EPI_QKV) {
                    ((u16*)Cout)[(size_t)row * ldc + col] = f2bf(vv + e0[col]);
                } else if constexpr (EPI == EPI_SCORES) {
                    ((float*)Cout)[(size_t)row * ldc + col] = vv * scale + e0[(size_t)row * 4096 + col];
                } else { // EPI_FINAL
                    float y = vv + e0[col] + e1[(size_t)row * 4096 + col];
                    ((float*)Cout)[(size_t)row * ldc + col] = y > 0.f ? y : 0.f;
                }
            }
        }
    }
#undef ISSUE_A
#undef ISSUE_B
#undef AR8
#undef PHASE
}

// ---------------- launch ----------------

extern "C" void kernel_launch(void* const* d_in, const int* in_sizes, int n_in,
                              void* d_out, int out_size, void* d_ws, size_t ws_size,
                              hipStream_t stream) {
    (void)in_sizes; (void)n_in; (void)out_size; (void)ws_size;
    const float* x   = (const float*)d_in[0];
    const float* A   = (const float*)d_in[1];
    const float* gm  = (const float*)d_in[2];
    const float* wts = (const float*)d_in[3];
    const float* Wst = (const float*)d_in[4];
    const float* bst = (const float*)d_in[5];
    const float* Wq  = (const float*)d_in[6];
    const float* bq  = (const float*)d_in[7];
    const float* Wk  = (const float*)d_in[8];
    const float* bk  = (const float*)d_in[9];
    const float* Wv  = (const float*)d_in[10];
    const float* bv  = (const float*)d_in[11];
    const float* Wo  = (const float*)d_in[12];
    const float* bo  = (const float*)d_in[13];
    const float* gamma = (const float*)d_in[14];
    const float* beta  = (const float*)d_in[15];
    float* out = (float*)d_out;
    char* ws = (char*)d_ws;

    const int N = 4096, DM = 1024;
    const size_t MB32 = 33554432UL;
    u16*   A_bf   = (u16*)(ws + 0);               // dead after inter GEMM
    u16*   A_bfT  = (u16*)(ws + MB32);            // dead after inter GEMM
    float* scores = (float*)(ws + 0);             // written phase 7
    u16*   x_bfT  = (u16*)(ws + 2 * MB32);        // dead after dng GEMM
    u16*   attn   = (u16*)(ws + 2 * MB32);        // written phase 8
    u16*   x_bf   = (u16*)(ws + 3 * MB32);        // dead after weighted GEMM
    u16*   WqkvT  = (u16*)(ws + 3 * MB32);        // written phase 4
    float* bqkv   = (float*)(ws + 3 * MB32 + 6291456UL);
    u16*   QKV    = (u16*)(ws + 3 * MB32 + 6307840UL);
    u16*   M_bf   = (u16*)(ws + 4 * MB32);        // dead after dng GEMM
    u16*   WallT  = (u16*)(ws + 0);               // [0,80MB) phase 3 (A_bf/A_bfT/x_bfT dead)
    u16*   V_T    = (u16*)(ws + 4 * MB32);        // written phase 6
    u16*   WoT    = (u16*)(ws + 4 * MB32 + 8388608UL);
    u16*   out_bf = (u16*)(ws + 4 * MB32 + 16777216UL);
    float* dng    = (float*)(ws + 5 * MB32);      // 64 MB, lives to end
    float* wxf    = (float*)(ws + 5 * MB32 + 67108864UL);
    u16*   h_bf   = (u16*)(ws + 5 * MB32 + 83886080UL);
    float* rowS   = (float*)(ws + 5 * MB32 + 92274688UL);
    float* colS   = (float*)(ws + 5 * MB32 + 92291072UL);

    // phase 0: conversions + degree sums
    k_convert_bf16<<<16384, 256, 0, stream>>>(A, A_bf, (long)N * N);
    k_transpose_f32_bf16<<<dim3(128, 128), 256, 0, stream>>>(A, A_bfT, N, N, N, N);
    k_convert_bf16<<<16384, 256, 0, stream>>>(x, x_bf, (long)N * N);
    k_transpose_f32_bf16<<<dim3(128, 128), 256, 0, stream>>>(x, x_bfT, N, N, N, N);
    k_rowsum<<<N, 256, 0, stream>>>(A, rowS);
    k_rowsum_bf16<<<N, 256, 0, stream>>>(A_bfT, colS);   // column sums of A via A^T row sums

    // phase 1: inter = A@A, epilogue builds M = A + sim + gm (bf16)
    gemm8<EPI_M_BUILD><<<dim3(16, 16), 512, 0, stream>>>(
        A_bf, A_bfT, N, N, N, N, M_bf, A, gm, rowS, colS, 0.f);

    // phase 2: dng = M @ x (fp32)
    gemm8<EPI_F32><<<dim3(16, 16), 512, 0, stream>>>(
        M_bf, x_bfT, N, N, N, N, dng, nullptr, nullptr, nullptr, nullptr, 0.f);

    // phase 3: weighted_x = sum_k w[:,k]*(x@W_k + b_k)
    // one flat GEMM x[4096,4096] @ WallT[10240,4096]^T with atomic fold into zeroed wxf
    for (int k = 0; k < 10; ++k)
        k_transpose_f32_bf16<<<dim3(32, 128), 256, 0, stream>>>(
            Wst + (size_t)k * N * DM, WallT + (size_t)k * DM * N, N, DM, DM, N);
    k_zero_f32<<<4096, 256, 0, stream>>>(wxf);
    gemm8<EPI_WEIGHTED><<<dim3(40, 16), 512, 0, stream>>>(
        x_bf, WallT, N, N, N, DM, wxf, wts, bst, nullptr, nullptr, 0.f);

    // phase 4: QKV weight prep + layernorm
    k_transpose_f32_bf16<<<dim3(32, 32), 256, 0, stream>>>(Wq, WqkvT, DM, DM, DM, DM);
    k_transpose_f32_bf16<<<dim3(32, 32), 256, 0, stream>>>(Wk, WqkvT + (size_t)DM * DM, DM, DM, DM, DM);
    k_transpose_f32_bf16<<<dim3(32, 32), 256, 0, stream>>>(Wv, WqkvT + 2 * (size_t)DM * DM, DM, DM, DM, DM);
    k_bias_concat<<<12, 256, 0, stream>>>(bq, bk, bv, bqkv);
    k_layernorm<<<N, 256, 0, stream>>>(wxf, gamma, beta, h_bf);

    // phase 5: QKV = h @ [Wq|Wk|Wv] + bias  (bf16, ldc=3072)
    gemm8<EPI_QKV><<<dim3(12, 16), 512, 0, stream>>>(
        h_bf, WqkvT, DM, DM, DM, 3072, QKV, bqkv, nullptr, nullptr, nullptr, 0.f);

    // phase 6: V^T
    k_transpose_u16<<<dim3(32, 128), 256, 0, stream>>>(QKV + 2048, V_T, N, DM, 3072, N);

    // phase 7: scores = Q@K^T/32 + dng (fp32)
    gemm8<EPI_SCORES><<<dim3(16, 16), 512, 0, stream>>>(
        QKV, QKV + 1024, DM, 3072, 3072, N, scores, dng, nullptr, nullptr, nullptr, 0.03125f);

    // phase 8: softmax rows -> attn (bf16)
    k_softmax<<<N, 256, 0, stream>>>(scores, attn);

    // phase 9: out = attn @ V (bf16) -- skinny N=1024: keep 128^2 m97 structure (256 blocks)
    gemm_bt<EPI_BF16><<<dim3(8, 32), 256, 0, stream>>>(
        attn, V_T, N, N, N, DM, out_bf, nullptr, nullptr, nullptr, nullptr, 0.f, 0, 0);

    // phase 10: y = relu(out @ Wo + bo + dng) -> d_out (fp32)
    k_transpose_f32_bf16<<<dim3(128, 32), 256, 0, stream>>>(Wo, WoT, DM, N, N, DM);
    gemm8<EPI_FINAL><<<dim3(16, 16), 512, 0, stream>>>(
        out_bf, WoT, DM, DM, DM, N, out, bo, dng, nullptr, nullptr, 0.f);
}